// Round 12
// baseline (266.905 us; speedup 1.0000x reference)
//
#include <hip/hip_runtime.h>
#include <stdint.h>
#include <stddef.h>

// Problem constants (B=4, T=2048, C=1024, H=16, hd=64)
#define TT 2048
#define CC 1024
#define BBATCH 4
#define HH 16
#define HD 64
#define MTOT (BBATCH * TT)   // 8192

typedef __bf16 bf16_t;
typedef __bf16 bf16x4 __attribute__((ext_vector_type(4)));
typedef __bf16 bf16x8 __attribute__((ext_vector_type(8)));
typedef float f32x4 __attribute__((ext_vector_type(4)));
typedef float f32x16 __attribute__((ext_vector_type(16)));

typedef const __attribute__((address_space(1))) uint32_t* as1_u32p;
typedef __attribute__((address_space(3))) uint32_t* as3_u32p;

__device__ __forceinline__ f32x4 mfma16(bf16x8 a, bf16x8 b, f32x4 c) {
  return __builtin_amdgcn_mfma_f32_16x16x32_bf16(a, b, c, 0, 0, 0);
}
__device__ __forceinline__ f32x16 mfma32(bf16x8 a, bf16x8 b, f32x16 c) {
  return __builtin_amdgcn_mfma_f32_32x32x16_bf16(a, b, c, 0, 0, 0);
}

// async global->LDS, 16B per lane; lds dest is wave-uniform base + lane*16
__device__ __forceinline__ void gload_lds16(void* lds, const void* g) {
  __builtin_amdgcn_global_load_lds((as1_u32p)g, (as3_u32p)lds, 16, 0, 0);
}

// Fragment read from [rows][32]-bf16 LDS tile (64B rows, swizzle (row>>1)&3).
__device__ __forceinline__ bf16x8 rd32(const char* t, int row, int lane) {
  int sl = (lane >> 4) ^ ((row >> 1) & 3);
  return *(const bf16x8*)(t + row * 64 + sl * 16);
}
// Fragment read from [rows][64]-bf16 LDS tile (128B rows, swizzle row&7), slot = 16B index.
__device__ __forceinline__ bf16x8 rd32r(const char* t, int row, int slot) {
  return *(const bf16x8*)(t + row * 128 + ((slot ^ (row & 7)) * 16));
}

// ---------------- kernel 1: split x (fp32 -> bf16 hi + bf16 lo) ----------------
__global__ void split_x_kernel(const float* __restrict__ x, bf16_t* __restrict__ xh,
                               bf16_t* __restrict__ xl, int n4) {
  int stride = gridDim.x * blockDim.x;
  for (int i = blockIdx.x * blockDim.x + threadIdx.x; i < n4; i += stride) {
    float4 v = ((const float4*)x)[i];
    float vv[4] = {v.x, v.y, v.z, v.w};
    bf16x4 hv, lv;
#pragma unroll
    for (int j = 0; j < 4; ++j) {
      bf16_t h = (bf16_t)vv[j];
      hv[j] = h;
      lv[j] = (bf16_t)(vv[j] - (float)h);
    }
    *(bf16x4*)(xh + (size_t)i * 4) = hv;
    *(bf16x4*)(xl + (size_t)i * 4) = lv;
  }
}

// ------------- kernel 2: transpose weights; split Wq/Wk, plain Wv/Wp -------------
__global__ void transpose_split_kernel(const float* __restrict__ Wq, const float* __restrict__ Wk,
                                       const float* __restrict__ Wv, const float* __restrict__ Wp,
                                       bf16_t* __restrict__ wqkh, bf16_t* __restrict__ wqkl,
                                       bf16_t* __restrict__ wv_t, bf16_t* __restrict__ wp_t) {
  __shared__ float tile[32][33];
  int mat = blockIdx.z;
  const float* W = (mat == 0) ? Wq : (mat == 1) ? Wk : (mat == 2) ? Wv : Wp;
  int tx = threadIdx.x, ty = threadIdx.y;
  int n0 = blockIdx.x * 32, k0 = blockIdx.y * 32;
#pragma unroll
  for (int j = 0; j < 32; j += 8)
    tile[ty + j][tx] = W[(size_t)(k0 + ty + j) * CC + n0 + tx];
  __syncthreads();
#pragma unroll
  for (int j = 0; j < 32; j += 8) {
    float v = tile[tx][ty + j];
    int n = n0 + ty + j, k = k0 + tx;
    if (mat <= 1) {
      bf16_t h = (bf16_t)v;
      size_t o = (size_t)(mat * CC + n) * CC + k;
      wqkh[o] = h;
      wqkl[o] = (bf16_t)(v - (float)h);
    } else {
      bf16_t* dst = (mat == 2) ? wv_t : wp_t;
      dst[(size_t)n * CC + k] = (bf16_t)v;
    }
  }
}

// ------- QK projection GEMM (round-4 best): 256x256, BK=32, 8 waves, dbuf + vmcnt(8) -------
__global__ __launch_bounds__(512, 2) void gemm_qk_kernel(
    const bf16_t* __restrict__ Ah, const bf16_t* __restrict__ Al,
    const bf16_t* __restrict__ Bh, const bf16_t* __restrict__ Bl,
    const float* __restrict__ bq, const float* __restrict__ bk,
    bf16_t* __restrict__ qh, bf16_t* __restrict__ ql,
    bf16_t* __restrict__ kh, bf16_t* __restrict__ kl) {
  __shared__ __align__(16) char s_ah[2][16384];
  __shared__ __align__(16) char s_al[2][16384];
  __shared__ __align__(16) char s_bh[2][16384];
  __shared__ __align__(16) char s_bl[2][16384];

  const int blk = blockIdx.x;
  const int bn = blk & 7;
  const int bm = blk >> 3;
  const int tid = threadIdx.x, w = tid >> 6, lane = tid & 63;
  const int wr = w >> 2, wc = w & 3;          // wave = (wr, wc) of 2x4 -> 128x64 output
  const int qi = lane & 15, hi = lane >> 4;

  const int c0 = w * 2, c1 = w * 2 + 1;
  const int srow0 = c0 * 16 + (lane >> 2);
  const int srow1 = c1 * 16 + (lane >> 2);
  const int ssl0 = (lane & 3) ^ ((srow0 >> 1) & 3);
  const int ssl1 = (lane & 3) ^ ((srow1 >> 1) & 3);
  const size_t a_off0 = (size_t)(bm * 256 + srow0) * CC + ssl0 * 8;
  const size_t a_off1 = (size_t)(bm * 256 + srow1) * CC + ssl1 * 8;
  const size_t b_off0 = (size_t)(bn * 256 + srow0) * CC + ssl0 * 8;
  const size_t b_off1 = (size_t)(bn * 256 + srow1) * CC + ssl1 * 8;

  f32x4 acc[8][4] = {};

#define STAGE_QK(buf, k0)                                        \
  do {                                                           \
    gload_lds16(s_ah[buf] + c0 * 1024, Ah + a_off0 + (k0));      \
    gload_lds16(s_ah[buf] + c1 * 1024, Ah + a_off1 + (k0));      \
    gload_lds16(s_al[buf] + c0 * 1024, Al + a_off0 + (k0));      \
    gload_lds16(s_al[buf] + c1 * 1024, Al + a_off1 + (k0));      \
    gload_lds16(s_bh[buf] + c0 * 1024, Bh + b_off0 + (k0));      \
    gload_lds16(s_bh[buf] + c1 * 1024, Bh + b_off1 + (k0));      \
    gload_lds16(s_bl[buf] + c0 * 1024, Bl + b_off0 + (k0));      \
    gload_lds16(s_bl[buf] + c1 * 1024, Bl + b_off1 + (k0));      \
  } while (0)

  STAGE_QK(0, 0);
  int cur = 0;
  for (int ks = 0; ks < 32; ++ks) {
    if (ks < 31) {
      STAGE_QK(cur ^ 1, (ks + 1) * 32);
      asm volatile("s_waitcnt vmcnt(8)" ::: "memory");  // current tile landed; prefetch in flight
    } else {
      asm volatile("s_waitcnt vmcnt(0)" ::: "memory");
    }
    __builtin_amdgcn_s_barrier();

    bf16x8 bfh[4], bfl[4];
#pragma unroll
    for (int ni = 0; ni < 4; ++ni) {
      int br = wc * 64 + ni * 16 + qi;
      bfh[ni] = rd32(s_bh[cur], br, lane);
      bfl[ni] = rd32(s_bl[cur], br, lane);
    }
    __builtin_amdgcn_s_setprio(1);
#pragma unroll
    for (int mi = 0; mi < 8; ++mi) {
      int ar = wr * 128 + mi * 16 + qi;
      bf16x8 ahf = rd32(s_ah[cur], ar, lane);
      bf16x8 alf = rd32(s_al[cur], ar, lane);
#pragma unroll
      for (int ni = 0; ni < 4; ++ni) {
        acc[mi][ni] = mfma16(ahf, bfh[ni], acc[mi][ni]);
        acc[mi][ni] = mfma16(ahf, bfl[ni], acc[mi][ni]);
        acc[mi][ni] = mfma16(alf, bfh[ni], acc[mi][ni]);
      }
    }
    __builtin_amdgcn_s_setprio(0);
    asm volatile("s_waitcnt lgkmcnt(0)" ::: "memory");
    __builtin_amdgcn_s_barrier();
    cur ^= 1;
  }
#undef STAGE_QK

  // epilogue: bias, Q-scale (1/sqrt(hd) * log2(e) -> exp2-unit logits), split hi/lo
  const int which = bn >> 2;  // 0: Q cols (bn 0..3), 1: K cols (bn 4..7)
  const float* bias = which ? bk : bq;
  bf16_t* oh = which ? kh : qh;
  bf16_t* ol = which ? kl : ql;
#pragma unroll
  for (int mi = 0; mi < 8; ++mi) {
#pragma unroll
    for (int ni = 0; ni < 4; ++ni) {
      const int col = bn * 256 + wc * 64 + ni * 16 + qi;
      const int c1i = col & 1023;
      const int h = c1i >> 6, d = c1i & 63;
#pragma unroll
      for (int r = 0; r < 4; ++r) {
        const int row = bm * 256 + wr * 128 + mi * 16 + hi * 4 + r;
        const int b = row >> 11, t = row & 2047;
        float v = acc[mi][ni][r] + bias[c1i];
        if (!which) v *= 0.18033688f;  // 0.125 * log2(e): softmax done in exp2
        const size_t off = ((size_t)(b * HH + h) * TT + t) * HD + d;
        bf16_t hv = (bf16_t)v;
        oh[off] = hv;
        ol[off] = (bf16_t)(v - (float)hv);
      }
    }
  }
}

// ---------------- GEMM: 128x128 tile, BK=32, 4 waves, 16x16x32 MFMA ----------------
// MODE 1: V projection, plain bf16, N=1024, writes vt [BH][64][T] (transposed)
// MODE 2: output projection, plain bf16 in, fp32 out [M][1024] + bias
template <int MODE>
__global__ __launch_bounds__(256) void gemm_kernel(
    const bf16_t* __restrict__ Ah,
    const bf16_t* __restrict__ Bh,
    const float* __restrict__ bias0,
    void* __restrict__ out0) {
  __shared__ __align__(16) char smem[2 * 8192];
  char* sAh = smem;
  char* sBh = smem + 8192;

  const int bn = blockIdx.x, bm = blockIdx.y;
  const int tid = threadIdx.x, w = tid >> 6, lane = tid & 63;
  const int wr = w >> 1, wc = w & 1;

  f32x4 acc[4][4] = {};

  for (int ks = 0; ks < 32; ++ks) {
    const int k0 = ks * 32;
    __syncthreads();
#pragma unroll
    for (int it = 0; it < 2; ++it) {
      int c = it * 4 + w;                 // 1KB chunk id, uniform per wave
      int row = c * 16 + (lane >> 2);     // tile-local row
      int sl = (lane & 3) ^ ((row >> 1) & 3);  // pre-swizzled source slot
      size_t aoff = (size_t)(bm * 128 + row) * CC + k0 + sl * 8;
      size_t boff = (size_t)(bn * 128 + row) * CC + k0 + sl * 8;
      gload_lds16(sAh + c * 1024, Ah + aoff);
      gload_lds16(sBh + c * 1024, Bh + boff);
    }
    __syncthreads();

    bf16x8 afh[4], bfh[4];
#pragma unroll
    for (int i = 0; i < 4; ++i) {
      int ar = wr * 64 + i * 16 + (lane & 15);
      int br = wc * 64 + i * 16 + (lane & 15);
      afh[i] = rd32(sAh, ar, lane);
      bfh[i] = rd32(sBh, br, lane);
    }
#pragma unroll
    for (int mi = 0; mi < 4; ++mi) {
#pragma unroll
      for (int ni = 0; ni < 4; ++ni) {
        acc[mi][ni] = mfma16(afh[mi], bfh[ni], acc[mi][ni]);
      }
    }
  }

#pragma unroll
  for (int mi = 0; mi < 4; ++mi) {
#pragma unroll
    for (int ni = 0; ni < 4; ++ni) {
      const int col = bn * 128 + wc * 64 + ni * 16 + (lane & 15);
#pragma unroll
      for (int r = 0; r < 4; ++r) {
        const int row = bm * 128 + wr * 64 + mi * 16 + (lane >> 4) * 4 + r;
        float v = acc[mi][ni][r];
        if (MODE == 1) {
          const int h = col >> 6, d = col & 63;
          const int b = row >> 11, t = row & 2047;
          float vv = v + bias0[col];
          ((bf16_t*)out0)[((size_t)(b * HH + h) * HD + d) * TT + t] = (bf16_t)vv;
        } else {
          ((float*)out0)[(size_t)row * CC + col] = v + bias0[col];
        }
      }
    }
  }
}

// ------- flash attention v8: v5 + split QK chains + exp2 softmax + setprio -------
// Grid 1024 = 16 qb-batches (heaviest first) x 64 bh. Block handles one 128-row q-block
// (4 waves x 32 q). bh <-> blk mod 64 fixed -> same XCD each qb-batch for K/V L2 reuse.
__global__ __launch_bounds__(256, 3) void attn_kernel(
    const bf16_t* __restrict__ qh, const bf16_t* __restrict__ ql,
    const bf16_t* __restrict__ kh, const bf16_t* __restrict__ kl,
    const bf16_t* __restrict__ vt, bf16_t* __restrict__ y) {
  __shared__ __align__(16) char s_kh[2][8192];
  __shared__ __align__(16) char s_kl[2][8192];
  __shared__ __align__(16) char s_vt[2][8192];

  const int blk = blockIdx.x;
  const int qb = 15 - (blk >> 6);                    // LPT: heaviest q-blocks first
  const int bh = (blk & 7) * 8 + ((blk >> 3) & 7);   // XCD-stable per bh
  const int b = bh >> 4, h = bh & 15;
  const int tid = threadIdx.x, w = tid >> 6, lane = tid & 63;
  const int l31 = lane & 31, hi = lane >> 5;

  // staging: wave w stages rows w*16 .. w*16+15 of each 64-row tile (2 gloads/tensor)
  const int strow0 = w * 16 + (lane >> 3);
  const int strow1 = strow0 + 8;
  const int sl0 = (lane & 7) ^ (strow0 & 7);
  const int sl1 = (lane & 7) ^ (strow1 & 7);
  // K rows sigma-permuted: LDS position r holds true kv = swap-bits-2,3(r)
  const int ksrow0 = (strow0 & ~12) | ((strow0 & 4) << 1) | ((strow0 & 8) >> 1);
  const int ksrow1 = (strow1 & ~12) | ((strow1 & 4) << 1) | ((strow1 & 8) >> 1);
  const size_t koff0 = ((size_t)bh * TT + ksrow0) * HD + sl0 * 8;
  const size_t koff1 = ((size_t)bh * TT + ksrow1) * HD + sl1 * 8;
  const size_t voff0 = ((size_t)bh * HD + strow0) * TT + sl0 * 8;
  const size_t voff1 = ((size_t)bh * HD + strow1) * TT + sl1 * 8;
  const int ch0 = (w * 2) * 1024, ch1 = (w * 2 + 1) * 1024;

#define STAGE_ATTN(buf, kt)                                                  \
  do {                                                                       \
    gload_lds16(s_kh[buf] + ch0, kh + koff0 + (size_t)(kt) * 64 * HD);       \
    gload_lds16(s_kh[buf] + ch1, kh + koff1 + (size_t)(kt) * 64 * HD);       \
    gload_lds16(s_kl[buf] + ch0, kl + koff0 + (size_t)(kt) * 64 * HD);       \
    gload_lds16(s_kl[buf] + ch1, kl + koff1 + (size_t)(kt) * 64 * HD);       \
    gload_lds16(s_vt[buf] + ch0, vt + voff0 + (size_t)(kt) * 64);            \
    gload_lds16(s_vt[buf] + ch1, vt + voff1 + (size_t)(kt) * 64);            \
  } while (0)

  const int ktmax = 2 * qb + 1;          // tiles 0..ktmax
  const int qrow0 = qb * 128 + w * 32;   // this wave's first q row
  const int qv = qrow0 + l31;            // this lane's q row

  // Q fragments (hi+lo): B-operand of 32x32x16: col=lane&31 -> q, k = kc*16 + hi*8 + j
  bf16x8 qhf[4], qlf[4];
#pragma unroll
  for (int kc = 0; kc < 4; ++kc) {
    size_t off = ((size_t)bh * TT + qv) * HD + kc * 16 + hi * 8;
    qhf[kc] = *(const bf16x8*)(qh + off);
    qlf[kc] = *(const bf16x8*)(ql + off);
  }

  // O^T accumulators: lane holds O[d][qv], d = dt*32 + (r&3) + 8*(r>>2) + 4*hi
  f32x16 o0 = {}, o1 = {};
  float m = -1e30f, l = 0.f;

  STAGE_ATTN(0, 0);
  int cur = 0;
  for (int kt = 0; kt <= ktmax; ++kt) {
    if (kt < ktmax) {
      STAGE_ATTN(cur ^ 1, kt + 1);
      asm volatile("s_waitcnt vmcnt(6)" ::: "memory");  // current tile landed
    } else {
      asm volatile("s_waitcnt vmcnt(0)" ::: "memory");
    }
    __builtin_amdgcn_s_barrier();

    const char* ckh = s_kh[cur];
    const char* ckl = s_kl[cur];
    const char* cvt = s_vt[cur];
    const bool active = (qrow0 + 31 >= kt * 64);  // wave-uniform
    if (active) {
      // S^T = K*Q^T (3-term). Two 6-deep chains per accumulator (halved MFMA
      // dependency latency vs one 12-deep chain), summed after.
      f32x16 s0a = {}, s0b = {}, s1a = {}, s1b = {};
      __builtin_amdgcn_s_setprio(1);
#pragma unroll
      for (int kc = 0; kc < 2; ++kc) {
        bf16x8 kfh = rd32r(ckh, l31, kc * 2 + hi);
        bf16x8 kfl = rd32r(ckl, l31, kc * 2 + hi);
        s0a = mfma32(kfh, qhf[kc], s0a);
        s0a = mfma32(kfl, qhf[kc], s0a);
        s0a = mfma32(kfh, qlf[kc], s0a);
      }
#pragma unroll
      for (int kc = 2; kc < 4; ++kc) {
        bf16x8 kfh = rd32r(ckh, l31, kc * 2 + hi);
        bf16x8 kfl = rd32r(ckl, l31, kc * 2 + hi);
        s0b = mfma32(kfh, qhf[kc], s0b);
        s0b = mfma32(kfl, qhf[kc], s0b);
        s0b = mfma32(kfh, qlf[kc], s0b);
      }
#pragma unroll
      for (int kc = 0; kc < 2; ++kc) {
        bf16x8 kfh = rd32r(ckh, 32 + l31, kc * 2 + hi);
        bf16x8 kfl = rd32r(ckl, 32 + l31, kc * 2 + hi);
        s1a = mfma32(kfh, qhf[kc], s1a);
        s1a = mfma32(kfl, qhf[kc], s1a);
        s1a = mfma32(kfh, qlf[kc], s1a);
      }
#pragma unroll
      for (int kc = 2; kc < 4; ++kc) {
        bf16x8 kfh = rd32r(ckh, 32 + l31, kc * 2 + hi);
        bf16x8 kfl = rd32r(ckl, 32 + l31, kc * 2 + hi);
        s1b = mfma32(kfh, qhf[kc], s1b);
        s1b = mfma32(kfl, qhf[kc], s1b);
        s1b = mfma32(kfh, qlf[kc], s1b);
      }
      __builtin_amdgcn_s_setprio(0);
      f32x16 s0 = s0a + s0b;
      f32x16 s1 = s1a + s1b;

      // causal mask. True kv of reg r, subtile c: (r&7) + 8*hi + 16*(r>>3) + 32*c
      if (kt * 64 + 63 > qrow0) {
#pragma unroll
        for (int r = 0; r < 16; ++r) {
          const int kvb = kt * 64 + (r & 7) + 8 * hi + 16 * (r >> 3);
          if (kvb > qv) s0[r] = -1e30f;
          if (kvb + 32 > qv) s1[r] = -1e30f;
        }
      }

      // row max: tree reduction (depth 5) + partner lane^32
      float t8[8];
#pragma unroll
      for (int r = 0; r < 8; ++r)
        t8[r] = fmaxf(fmaxf(s0[r], s0[r + 8]), fmaxf(s1[r], s1[r + 8]));
      float t4a = fmaxf(t8[0], t8[4]), t4b = fmaxf(t8[1], t8[5]);
      float t4c = fmaxf(t8[2], t8[6]), t4d = fmaxf(t8[3], t8[7]);
      float tmax = fmaxf(fmaxf(t4a, t4b), fmaxf(t4c, t4d));
      tmax = fmaxf(tmax, __shfl_xor(tmax, 32));

      // exact skip-rescale: if no lane's max grew, sc==1 identically
      const float mnew = fmaxf(m, tmax);
      if (!__all(tmax <= m)) {
        const float sc = exp2f(m - mnew);
        l *= sc;
#pragma unroll
        for (int r = 0; r < 16; ++r) { o0[r] *= sc; o1[r] *= sc; }
        m = mnew;
      }

      // P = exp2(S - m) (logits are pre-scaled by log2 e); row-sum via tree
#pragma unroll
      for (int r = 0; r < 16; ++r) {
        s0[r] = exp2f(s0[r] - m);
        s1[r] = exp2f(s1[r] - m);
      }
      float p8[8];
#pragma unroll
      for (int r = 0; r < 8; ++r)
        p8[r] = (s0[r] + s0[r + 8]) + (s1[r] + s1[r + 8]);
      float ps = ((p8[0] + p8[1]) + (p8[2] + p8[3])) + ((p8[4] + p8[5]) + (p8[6] + p8[7]));
      ps += __shfl_xor(ps, 32);
      l += ps;

      // P fragments: pa[cc] = bf16(S regs 8*(cc&1)+0..7 of subtile cc>>1)
      bf16x8 pa[4];
#pragma unroll
      for (int cc = 0; cc < 4; ++cc) {
#pragma unroll
        for (int j = 0; j < 8; ++j)
          pa[cc][j] = (bf16_t)((cc >> 1) ? s1[8 * (cc & 1) + j] : s0[8 * (cc & 1) + j]);
      }

      // O^T += V^T * P^T: A = V rows (d), k = kv chunk cc
      __builtin_amdgcn_s_setprio(1);
#pragma unroll
      for (int cc = 0; cc < 4; ++cc) {
        bf16x8 vf0 = rd32r(cvt, l31, cc * 2 + hi);
        bf16x8 vf1 = rd32r(cvt, 32 + l31, cc * 2 + hi);
        o0 = mfma32(vf0, pa[cc], o0);
        o1 = mfma32(vf1, pa[cc], o1);
      }
      __builtin_amdgcn_s_setprio(0);
    }

    asm volatile("s_waitcnt lgkmcnt(0)" ::: "memory");
    __builtin_amdgcn_s_barrier();
    cur ^= 1;
  }

  // epilogue: lane holds O[d][qv] for d = dt*32 + g*8 + hi*4 + (0..3)
  const float inv = 1.f / l;
  bf16_t* yb = y + (size_t)(b * TT + qv) * CC + h * HD;
#pragma unroll
  for (int g = 0; g < 4; ++g) {
    bf16x4 ov0, ov1;
#pragma unroll
    for (int r = 0; r < 4; ++r) {
      ov0[r] = (bf16_t)(o0[g * 4 + r] * inv);
      ov1[r] = (bf16_t)(o1[g * 4 + r] * inv);
    }
    *(bf16x4*)(yb + g * 8 + hi * 4) = ov0;
    *(bf16x4*)(yb + 32 + g * 8 + hi * 4) = ov1;
  }
#undef STAGE_ATTN
}

// ---------------- launch ----------------
extern "C" void kernel_launch(void* const* d_in, const int* in_sizes, int n_in,
                              void* d_out, int out_size, void* d_ws, size_t ws_size,
                              hipStream_t stream) {
  (void)in_sizes; (void)n_in; (void)out_size; (void)ws_size;
  const float* x  = (const float*)d_in[0];
  const float* Wq = (const float*)d_in[1];
  const float* bq = (const float*)d_in[2];
  const float* Wk = (const float*)d_in[3];
  const float* bk = (const float*)d_in[4];
  const float* Wv = (const float*)d_in[5];
  const float* bv = (const float*)d_in[6];
  const float* Wp = (const float*)d_in[7];
  const float* bp = (const float*)d_in[8];

  char* ws = (char*)d_ws;
  const size_t MB = 1024 * 1024;
  bf16_t* xh   = (bf16_t*)(ws + 0 * MB);    // [8192][1024]
  bf16_t* xl   = (bf16_t*)(ws + 16 * MB);   // [8192][1024]
  bf16_t* wqkh = (bf16_t*)(ws + 32 * MB);   // [2048][1024] (Wq^T rows 0..1023, Wk^T rows 1024..2047)
  bf16_t* wqkl = (bf16_t*)(ws + 36 * MB);
  bf16_t* wv_t = (bf16_t*)(ws + 40 * MB);   // [1024][1024]
  bf16_t* wp_t = (bf16_t*)(ws + 42 * MB);   // [1024][1024]
  bf16_t* qhw  = (bf16_t*)(ws + 44 * MB);   // [64][2048][64]
  bf16_t* qlw  = (bf16_t*)(ws + 60 * MB);
  bf16_t* khw  = (bf16_t*)(ws + 76 * MB);
  bf16_t* klw  = (bf16_t*)(ws + 92 * MB);
  bf16_t* vtw  = (bf16_t*)(ws + 108 * MB);  // [64][64][2048] (V transposed per head)
  bf16_t* yw   = (bf16_t*)(ws + 124 * MB);  // [8192][1024]

  split_x_kernel<<<2048, 256, 0, stream>>>(x, xh, xl, MTOT * CC / 4);
  transpose_split_kernel<<<dim3(32, 32, 4), dim3(32, 8), 0, stream>>>(
      Wq, Wk, Wv, Wp, wqkh, wqkl, wv_t, wp_t);
  gemm_qk_kernel<<<256, 512, 0, stream>>>(
      xh, xl, wqkh, wqkl, bq, bk, qhw, qlw, khw, klw);
  gemm_kernel<1><<<dim3(8, 64), 256, 0, stream>>>(
      xh, wv_t, bv, vtw);
  attn_kernel<<<1024, 256, 0, stream>>>(qhw, qlw, khw, klw, vtw, yw);
  gemm_kernel<2><<<dim3(8, 64), 256, 0, stream>>>(
      yw, wp_t, bp, d_out);
}

// Round 13
// 259.960 us; speedup vs baseline: 1.0267x; 1.0267x over previous
//
#include <hip/hip_runtime.h>
#include <stdint.h>
#include <stddef.h>

// Problem constants (B=4, T=2048, C=1024, H=16, hd=64)
#define TT 2048
#define CC 1024
#define BBATCH 4
#define HH 16
#define HD 64
#define MTOT (BBATCH * TT)   // 8192

typedef __bf16 bf16_t;
typedef __bf16 bf16x4 __attribute__((ext_vector_type(4)));
typedef __bf16 bf16x8 __attribute__((ext_vector_type(8)));
typedef float f32x4 __attribute__((ext_vector_type(4)));
typedef float f32x16 __attribute__((ext_vector_type(16)));

typedef const __attribute__((address_space(1))) uint32_t* as1_u32p;
typedef __attribute__((address_space(3))) uint32_t* as3_u32p;

__device__ __forceinline__ f32x4 mfma16(bf16x8 a, bf16x8 b, f32x4 c) {
  return __builtin_amdgcn_mfma_f32_16x16x32_bf16(a, b, c, 0, 0, 0);
}
__device__ __forceinline__ f32x16 mfma32(bf16x8 a, bf16x8 b, f32x16 c) {
  return __builtin_amdgcn_mfma_f32_32x32x16_bf16(a, b, c, 0, 0, 0);
}

// async global->LDS, 16B per lane; lds dest is wave-uniform base + lane*16
__device__ __forceinline__ void gload_lds16(void* lds, const void* g) {
  __builtin_amdgcn_global_load_lds((as1_u32p)g, (as3_u32p)lds, 16, 0, 0);
}

// Fragment read from [rows][32]-bf16 LDS tile (64B rows, swizzle (row>>1)&3).
__device__ __forceinline__ bf16x8 rd32(const char* t, int row, int lane) {
  int sl = (lane >> 4) ^ ((row >> 1) & 3);
  return *(const bf16x8*)(t + row * 64 + sl * 16);
}
// Fragment read from [rows][64]-bf16 LDS tile (128B rows, swizzle row&7), slot = 16B index.
__device__ __forceinline__ bf16x8 rd32r(const char* t, int row, int slot) {
  return *(const bf16x8*)(t + row * 128 + ((slot ^ (row & 7)) * 16));
}

// ---------------- kernel 1: split x (fp32 -> bf16 hi + bf16 lo) ----------------
__global__ void split_x_kernel(const float* __restrict__ x, bf16_t* __restrict__ xh,
                               bf16_t* __restrict__ xl, int n4) {
  int stride = gridDim.x * blockDim.x;
  for (int i = blockIdx.x * blockDim.x + threadIdx.x; i < n4; i += stride) {
    float4 v = ((const float4*)x)[i];
    float vv[4] = {v.x, v.y, v.z, v.w};
    bf16x4 hv, lv;
#pragma unroll
    for (int j = 0; j < 4; ++j) {
      bf16_t h = (bf16_t)vv[j];
      hv[j] = h;
      lv[j] = (bf16_t)(vv[j] - (float)h);
    }
    *(bf16x4*)(xh + (size_t)i * 4) = hv;
    *(bf16x4*)(xl + (size_t)i * 4) = lv;
  }
}

// ------------- kernel 2: transpose weights; split Wq/Wk, plain Wv/Wp -------------
__global__ void transpose_split_kernel(const float* __restrict__ Wq, const float* __restrict__ Wk,
                                       const float* __restrict__ Wv, const float* __restrict__ Wp,
                                       bf16_t* __restrict__ wqkh, bf16_t* __restrict__ wqkl,
                                       bf16_t* __restrict__ wv_t, bf16_t* __restrict__ wp_t) {
  __shared__ float tile[32][33];
  int mat = blockIdx.z;
  const float* W = (mat == 0) ? Wq : (mat == 1) ? Wk : (mat == 2) ? Wv : Wp;
  int tx = threadIdx.x, ty = threadIdx.y;
  int n0 = blockIdx.x * 32, k0 = blockIdx.y * 32;
#pragma unroll
  for (int j = 0; j < 32; j += 8)
    tile[ty + j][tx] = W[(size_t)(k0 + ty + j) * CC + n0 + tx];
  __syncthreads();
#pragma unroll
  for (int j = 0; j < 32; j += 8) {
    float v = tile[tx][ty + j];
    int n = n0 + ty + j, k = k0 + tx;
    if (mat <= 1) {
      bf16_t h = (bf16_t)v;
      size_t o = (size_t)(mat * CC + n) * CC + k;
      wqkh[o] = h;
      wqkl[o] = (bf16_t)(v - (float)h);
    } else {
      bf16_t* dst = (mat == 2) ? wv_t : wp_t;
      dst[(size_t)n * CC + k] = (bf16_t)v;
    }
  }
}

// ------- QK projection GEMM (round-4 best): 256x256, BK=32, 8 waves, dbuf + vmcnt(8) -------
__global__ __launch_bounds__(512, 2) void gemm_qk_kernel(
    const bf16_t* __restrict__ Ah, const bf16_t* __restrict__ Al,
    const bf16_t* __restrict__ Bh, const bf16_t* __restrict__ Bl,
    const float* __restrict__ bq, const float* __restrict__ bk,
    bf16_t* __restrict__ qh, bf16_t* __restrict__ ql,
    bf16_t* __restrict__ kh, bf16_t* __restrict__ kl) {
  __shared__ __align__(16) char s_ah[2][16384];
  __shared__ __align__(16) char s_al[2][16384];
  __shared__ __align__(16) char s_bh[2][16384];
  __shared__ __align__(16) char s_bl[2][16384];

  const int blk = blockIdx.x;
  const int bn = blk & 7;
  const int bm = blk >> 3;
  const int tid = threadIdx.x, w = tid >> 6, lane = tid & 63;
  const int wr = w >> 2, wc = w & 3;          // wave = (wr, wc) of 2x4 -> 128x64 output
  const int qi = lane & 15, hi = lane >> 4;

  const int c0 = w * 2, c1 = w * 2 + 1;
  const int srow0 = c0 * 16 + (lane >> 2);
  const int srow1 = c1 * 16 + (lane >> 2);
  const int ssl0 = (lane & 3) ^ ((srow0 >> 1) & 3);
  const int ssl1 = (lane & 3) ^ ((srow1 >> 1) & 3);
  const size_t a_off0 = (size_t)(bm * 256 + srow0) * CC + ssl0 * 8;
  const size_t a_off1 = (size_t)(bm * 256 + srow1) * CC + ssl1 * 8;
  const size_t b_off0 = (size_t)(bn * 256 + srow0) * CC + ssl0 * 8;
  const size_t b_off1 = (size_t)(bn * 256 + srow1) * CC + ssl1 * 8;

  f32x4 acc[8][4] = {};

#define STAGE_QK(buf, k0)                                        \
  do {                                                           \
    gload_lds16(s_ah[buf] + c0 * 1024, Ah + a_off0 + (k0));      \
    gload_lds16(s_ah[buf] + c1 * 1024, Ah + a_off1 + (k0));      \
    gload_lds16(s_al[buf] + c0 * 1024, Al + a_off0 + (k0));      \
    gload_lds16(s_al[buf] + c1 * 1024, Al + a_off1 + (k0));      \
    gload_lds16(s_bh[buf] + c0 * 1024, Bh + b_off0 + (k0));      \
    gload_lds16(s_bh[buf] + c1 * 1024, Bh + b_off1 + (k0));      \
    gload_lds16(s_bl[buf] + c0 * 1024, Bl + b_off0 + (k0));      \
    gload_lds16(s_bl[buf] + c1 * 1024, Bl + b_off1 + (k0));      \
  } while (0)

  STAGE_QK(0, 0);
  int cur = 0;
  for (int ks = 0; ks < 32; ++ks) {
    if (ks < 31) {
      STAGE_QK(cur ^ 1, (ks + 1) * 32);
      asm volatile("s_waitcnt vmcnt(8)" ::: "memory");  // current tile landed; prefetch in flight
    } else {
      asm volatile("s_waitcnt vmcnt(0)" ::: "memory");
    }
    __builtin_amdgcn_s_barrier();

    bf16x8 bfh[4], bfl[4];
#pragma unroll
    for (int ni = 0; ni < 4; ++ni) {
      int br = wc * 64 + ni * 16 + qi;
      bfh[ni] = rd32(s_bh[cur], br, lane);
      bfl[ni] = rd32(s_bl[cur], br, lane);
    }
    __builtin_amdgcn_s_setprio(1);
#pragma unroll
    for (int mi = 0; mi < 8; ++mi) {
      int ar = wr * 128 + mi * 16 + qi;
      bf16x8 ahf = rd32(s_ah[cur], ar, lane);
      bf16x8 alf = rd32(s_al[cur], ar, lane);
#pragma unroll
      for (int ni = 0; ni < 4; ++ni) {
        acc[mi][ni] = mfma16(ahf, bfh[ni], acc[mi][ni]);
        acc[mi][ni] = mfma16(ahf, bfl[ni], acc[mi][ni]);
        acc[mi][ni] = mfma16(alf, bfh[ni], acc[mi][ni]);
      }
    }
    __builtin_amdgcn_s_setprio(0);
    asm volatile("s_waitcnt lgkmcnt(0)" ::: "memory");
    __builtin_amdgcn_s_barrier();
    cur ^= 1;
  }
#undef STAGE_QK

  // epilogue: bias, Q-scale (1/sqrt(hd) * log2(e) -> exp2-unit logits), split hi/lo
  const int which = bn >> 2;  // 0: Q cols (bn 0..3), 1: K cols (bn 4..7)
  const float* bias = which ? bk : bq;
  bf16_t* oh = which ? kh : qh;
  bf16_t* ol = which ? kl : ql;
#pragma unroll
  for (int mi = 0; mi < 8; ++mi) {
#pragma unroll
    for (int ni = 0; ni < 4; ++ni) {
      const int col = bn * 256 + wc * 64 + ni * 16 + qi;
      const int c1i = col & 1023;
      const int h = c1i >> 6, d = c1i & 63;
#pragma unroll
      for (int r = 0; r < 4; ++r) {
        const int row = bm * 256 + wr * 128 + mi * 16 + hi * 4 + r;
        const int b = row >> 11, t = row & 2047;
        float v = acc[mi][ni][r] + bias[c1i];
        if (!which) v *= 0.18033688f;  // 0.125 * log2(e): softmax done in exp2
        const size_t off = ((size_t)(b * HH + h) * TT + t) * HD + d;
        bf16_t hv = (bf16_t)v;
        oh[off] = hv;
        ol[off] = (bf16_t)(v - (float)hv);
      }
    }
  }
}

// ---------------- GEMM: 128x128 tile, BK=32, 4 waves, 16x16x32 MFMA ----------------
// MODE 1: V projection, plain bf16, N=1024, writes vt [BH][64][T] (transposed)
// MODE 2: output projection, plain bf16 in, fp32 out [M][1024] + bias
template <int MODE>
__global__ __launch_bounds__(256) void gemm_kernel(
    const bf16_t* __restrict__ Ah,
    const bf16_t* __restrict__ Bh,
    const float* __restrict__ bias0,
    void* __restrict__ out0) {
  __shared__ __align__(16) char smem[2 * 8192];
  char* sAh = smem;
  char* sBh = smem + 8192;

  const int bn = blockIdx.x, bm = blockIdx.y;
  const int tid = threadIdx.x, w = tid >> 6, lane = tid & 63;
  const int wr = w >> 1, wc = w & 1;

  f32x4 acc[4][4] = {};

  for (int ks = 0; ks < 32; ++ks) {
    const int k0 = ks * 32;
    __syncthreads();
#pragma unroll
    for (int it = 0; it < 2; ++it) {
      int c = it * 4 + w;                 // 1KB chunk id, uniform per wave
      int row = c * 16 + (lane >> 2);     // tile-local row
      int sl = (lane & 3) ^ ((row >> 1) & 3);  // pre-swizzled source slot
      size_t aoff = (size_t)(bm * 128 + row) * CC + k0 + sl * 8;
      size_t boff = (size_t)(bn * 128 + row) * CC + k0 + sl * 8;
      gload_lds16(sAh + c * 1024, Ah + aoff);
      gload_lds16(sBh + c * 1024, Bh + boff);
    }
    __syncthreads();

    bf16x8 afh[4], bfh[4];
#pragma unroll
    for (int i = 0; i < 4; ++i) {
      int ar = wr * 64 + i * 16 + (lane & 15);
      int br = wc * 64 + i * 16 + (lane & 15);
      afh[i] = rd32(sAh, ar, lane);
      bfh[i] = rd32(sBh, br, lane);
    }
#pragma unroll
    for (int mi = 0; mi < 4; ++mi) {
#pragma unroll
      for (int ni = 0; ni < 4; ++ni) {
        acc[mi][ni] = mfma16(afh[mi], bfh[ni], acc[mi][ni]);
      }
    }
  }

#pragma unroll
  for (int mi = 0; mi < 4; ++mi) {
#pragma unroll
    for (int ni = 0; ni < 4; ++ni) {
      const int col = bn * 128 + wc * 64 + ni * 16 + (lane & 15);
#pragma unroll
      for (int r = 0; r < 4; ++r) {
        const int row = bm * 128 + wr * 64 + mi * 16 + (lane >> 4) * 4 + r;
        float v = acc[mi][ni][r];
        if (MODE == 1) {
          const int h = col >> 6, d = col & 63;
          const int b = row >> 11, t = row & 2047;
          float vv = v + bias0[col];
          ((bf16_t*)out0)[((size_t)(b * HH + h) * HD + d) * TT + t] = (bf16_t)vv;
        } else {
          ((float*)out0)[(size_t)row * CC + col] = v + bias0[col];
        }
      }
    }
  }
}

// ------- flash attention v5.1 (round-8 best + exp2 softmax): 32x32 MFMA, in-reg P -------
// Grid 1024 = 16 qb-batches (heaviest first) x 64 bh. Block handles one 128-row q-block
// (4 waves x 32 q). bh <-> blk mod 64 fixed -> same XCD each qb-batch for K/V L2 reuse.
// Logits arrive pre-scaled by log2(e) (folded into Q projection) -> bare v_exp_f32.
__global__ __launch_bounds__(256, 3) void attn_kernel(
    const bf16_t* __restrict__ qh, const bf16_t* __restrict__ ql,
    const bf16_t* __restrict__ kh, const bf16_t* __restrict__ kl,
    const bf16_t* __restrict__ vt, bf16_t* __restrict__ y) {
  __shared__ __align__(16) char s_kh[2][8192];
  __shared__ __align__(16) char s_kl[2][8192];
  __shared__ __align__(16) char s_vt[2][8192];

  const int blk = blockIdx.x;
  const int qb = 15 - (blk >> 6);                    // LPT: heaviest q-blocks first
  const int bh = (blk & 7) * 8 + ((blk >> 3) & 7);   // XCD-stable per bh
  const int b = bh >> 4, h = bh & 15;
  const int tid = threadIdx.x, w = tid >> 6, lane = tid & 63;
  const int l31 = lane & 31, hi = lane >> 5;

  // staging: wave w stages rows w*16 .. w*16+15 of each 64-row tile (2 gloads/tensor)
  const int strow0 = w * 16 + (lane >> 3);
  const int strow1 = strow0 + 8;
  const int sl0 = (lane & 7) ^ (strow0 & 7);
  const int sl1 = (lane & 7) ^ (strow1 & 7);
  // K rows sigma-permuted: LDS position r holds true kv = swap-bits-2,3(r)
  const int ksrow0 = (strow0 & ~12) | ((strow0 & 4) << 1) | ((strow0 & 8) >> 1);
  const int ksrow1 = (strow1 & ~12) | ((strow1 & 4) << 1) | ((strow1 & 8) >> 1);
  const size_t koff0 = ((size_t)bh * TT + ksrow0) * HD + sl0 * 8;
  const size_t koff1 = ((size_t)bh * TT + ksrow1) * HD + sl1 * 8;
  const size_t voff0 = ((size_t)bh * HD + strow0) * TT + sl0 * 8;
  const size_t voff1 = ((size_t)bh * HD + strow1) * TT + sl1 * 8;
  const int ch0 = (w * 2) * 1024, ch1 = (w * 2 + 1) * 1024;

#define STAGE_ATTN(buf, kt)                                                  \
  do {                                                                       \
    gload_lds16(s_kh[buf] + ch0, kh + koff0 + (size_t)(kt) * 64 * HD);       \
    gload_lds16(s_kh[buf] + ch1, kh + koff1 + (size_t)(kt) * 64 * HD);       \
    gload_lds16(s_kl[buf] + ch0, kl + koff0 + (size_t)(kt) * 64 * HD);       \
    gload_lds16(s_kl[buf] + ch1, kl + koff1 + (size_t)(kt) * 64 * HD);       \
    gload_lds16(s_vt[buf] + ch0, vt + voff0 + (size_t)(kt) * 64);            \
    gload_lds16(s_vt[buf] + ch1, vt + voff1 + (size_t)(kt) * 64);            \
  } while (0)

  const int ktmax = 2 * qb + 1;          // tiles 0..ktmax
  const int qrow0 = qb * 128 + w * 32;   // this wave's first q row
  const int qv = qrow0 + l31;            // this lane's q row

  // Q fragments (hi+lo): B-operand of 32x32x16: col=lane&31 -> q, k = kc*16 + hi*8 + j
  bf16x8 qhf[4], qlf[4];
#pragma unroll
  for (int kc = 0; kc < 4; ++kc) {
    size_t off = ((size_t)bh * TT + qv) * HD + kc * 16 + hi * 8;
    qhf[kc] = *(const bf16x8*)(qh + off);
    qlf[kc] = *(const bf16x8*)(ql + off);
  }

  // O^T accumulators: lane holds O[d][qv], d = dt*32 + (r&3) + 8*(r>>2) + 4*hi
  f32x16 o0 = {}, o1 = {};
  float m = -1e30f, l = 0.f;

  STAGE_ATTN(0, 0);
  int cur = 0;
  for (int kt = 0; kt <= ktmax; ++kt) {
    if (kt < ktmax) {
      STAGE_ATTN(cur ^ 1, kt + 1);
      asm volatile("s_waitcnt vmcnt(6)" ::: "memory");  // current tile landed
    } else {
      asm volatile("s_waitcnt vmcnt(0)" ::: "memory");
    }
    __builtin_amdgcn_s_barrier();

    const char* ckh = s_kh[cur];
    const char* ckl = s_kl[cur];
    const char* cvt = s_vt[cur];
    const bool active = (qrow0 + 31 >= kt * 64);  // wave-uniform
    if (active) {
      // S^T = K*Q^T (3-term). Subtile c covers LDS K rows c*32..c*32+31.
      f32x16 s0 = {}, s1 = {};
#pragma unroll
      for (int kc = 0; kc < 4; ++kc) {
        bf16x8 kfh = rd32r(ckh, l31, kc * 2 + hi);
        bf16x8 kfl = rd32r(ckl, l31, kc * 2 + hi);
        s0 = mfma32(kfh, qhf[kc], s0);
        s0 = mfma32(kfl, qhf[kc], s0);
        s0 = mfma32(kfh, qlf[kc], s0);
      }
#pragma unroll
      for (int kc = 0; kc < 4; ++kc) {
        bf16x8 kfh = rd32r(ckh, 32 + l31, kc * 2 + hi);
        bf16x8 kfl = rd32r(ckl, 32 + l31, kc * 2 + hi);
        s1 = mfma32(kfh, qhf[kc], s1);
        s1 = mfma32(kfl, qhf[kc], s1);
        s1 = mfma32(kfh, qlf[kc], s1);
      }

      // causal mask. True kv of reg r, subtile c: (r&7) + 8*hi + 16*(r>>3) + 32*c
      if (kt * 64 + 63 > qrow0) {
#pragma unroll
        for (int r = 0; r < 16; ++r) {
          const int kvb = kt * 64 + (r & 7) + 8 * hi + 16 * (r >> 3);
          if (kvb > qv) s0[r] = -1e30f;
          if (kvb + 32 > qv) s1[r] = -1e30f;
        }
      }

      // row max: tree reduction (depth 5) + partner lane^32
      float t8[8];
#pragma unroll
      for (int r = 0; r < 8; ++r)
        t8[r] = fmaxf(fmaxf(s0[r], s0[r + 8]), fmaxf(s1[r], s1[r + 8]));
      float t4a = fmaxf(t8[0], t8[4]), t4b = fmaxf(t8[1], t8[5]);
      float t4c = fmaxf(t8[2], t8[6]), t4d = fmaxf(t8[3], t8[7]);
      float tmax = fmaxf(fmaxf(t4a, t4b), fmaxf(t4c, t4d));
      tmax = fmaxf(tmax, __shfl_xor(tmax, 32));

      // exact skip-rescale: if no lane's max grew, sc==1 identically
      const float mnew = fmaxf(m, tmax);
      if (!__all(tmax <= m)) {
        const float sc = exp2f(m - mnew);
        l *= sc;
#pragma unroll
        for (int r = 0; r < 16; ++r) { o0[r] *= sc; o1[r] *= sc; }
        m = mnew;
      }

      // P = exp2(S - m) (logits pre-scaled by log2 e); row-sum via tree
#pragma unroll
      for (int r = 0; r < 16; ++r) {
        s0[r] = exp2f(s0[r] - m);
        s1[r] = exp2f(s1[r] - m);
      }
      float p8[8];
#pragma unroll
      for (int r = 0; r < 8; ++r)
        p8[r] = (s0[r] + s0[r + 8]) + (s1[r] + s1[r + 8]);
      float ps = ((p8[0] + p8[1]) + (p8[2] + p8[3])) + ((p8[4] + p8[5]) + (p8[6] + p8[7]));
      ps += __shfl_xor(ps, 32);
      l += ps;

      // P fragments: pa[cc] = bf16(S regs 8*(cc&1)+0..7 of subtile cc>>1)
      bf16x8 pa[4];
#pragma unroll
      for (int cc = 0; cc < 4; ++cc) {
#pragma unroll
        for (int j = 0; j < 8; ++j)
          pa[cc][j] = (bf16_t)((cc >> 1) ? s1[8 * (cc & 1) + j] : s0[8 * (cc & 1) + j]);
      }

      // O^T += V^T * P^T: A = V rows (d), k = kv chunk cc
#pragma unroll
      for (int cc = 0; cc < 4; ++cc) {
        bf16x8 vf0 = rd32r(cvt, l31, cc * 2 + hi);
        bf16x8 vf1 = rd32r(cvt, 32 + l31, cc * 2 + hi);
        o0 = mfma32(vf0, pa[cc], o0);
        o1 = mfma32(vf1, pa[cc], o1);
      }
    }

    asm volatile("s_waitcnt lgkmcnt(0)" ::: "memory");
    __builtin_amdgcn_s_barrier();
    cur ^= 1;
  }

  // epilogue: lane holds O[d][qv] for d = dt*32 + g*8 + hi*4 + (0..3)
  const float inv = 1.f / l;
  bf16_t* yb = y + (size_t)(b * TT + qv) * CC + h * HD;
#pragma unroll
  for (int g = 0; g < 4; ++g) {
    bf16x4 ov0, ov1;
#pragma unroll
    for (int r = 0; r < 4; ++r) {
      ov0[r] = (bf16_t)(o0[g * 4 + r] * inv);
      ov1[r] = (bf16_t)(o1[g * 4 + r] * inv);
    }
    *(bf16x4*)(yb + g * 8 + hi * 4) = ov0;
    *(bf16x4*)(yb + 32 + g * 8 + hi * 4) = ov1;
  }
#undef STAGE_ATTN
}

// ---------------- launch ----------------
extern "C" void kernel_launch(void* const* d_in, const int* in_sizes, int n_in,
                              void* d_out, int out_size, void* d_ws, size_t ws_size,
                              hipStream_t stream) {
  (void)in_sizes; (void)n_in; (void)out_size; (void)ws_size;
  const float* x  = (const float*)d_in[0];
  const float* Wq = (const float*)d_in[1];
  const float* bq = (const float*)d_in[2];
  const float* Wk = (const float*)d_in[3];
  const float* bk = (const float*)d_in[4];
  const float* Wv = (const float*)d_in[5];
  const float* bv = (const float*)d_in[6];
  const float* Wp = (const float*)d_in[7];
  const float* bp = (const float*)d_in[8];

  char* ws = (char*)d_ws;
  const size_t MB = 1024 * 1024;
  bf16_t* xh   = (bf16_t*)(ws + 0 * MB);    // [8192][1024]
  bf16_t* xl   = (bf16_t*)(ws + 16 * MB);   // [8192][1024]
  bf16_t* wqkh = (bf16_t*)(ws + 32 * MB);   // [2048][1024] (Wq^T rows 0..1023, Wk^T rows 1024..2047)
  bf16_t* wqkl = (bf16_t*)(ws + 36 * MB);
  bf16_t* wv_t = (bf16_t*)(ws + 40 * MB);   // [1024][1024]
  bf16_t* wp_t = (bf16_t*)(ws + 42 * MB);   // [1024][1024]
  bf16_t* qhw  = (bf16_t*)(ws + 44 * MB);   // [64][2048][64]
  bf16_t* qlw  = (bf16_t*)(ws + 60 * MB);
  bf16_t* khw  = (bf16_t*)(ws + 76 * MB);
  bf16_t* klw  = (bf16_t*)(ws + 92 * MB);
  bf16_t* vtw  = (bf16_t*)(ws + 108 * MB);  // [64][64][2048] (V transposed per head)
  bf16_t* yw   = (bf16_t*)(ws + 124 * MB);  // [8192][1024]

  split_x_kernel<<<2048, 256, 0, stream>>>(x, xh, xl, MTOT * CC / 4);
  transpose_split_kernel<<<dim3(32, 32, 4), dim3(32, 8), 0, stream>>>(
      Wq, Wk, Wv, Wp, wqkh, wqkl, wv_t, wp_t);
  gemm_qk_kernel<<<256, 512, 0, stream>>>(
      xh, xl, wqkh, wqkl, bq, bk, qhw, qlw, khw, klw);
  gemm_kernel<1><<<dim3(8, 64), 256, 0, stream>>>(
      xh, wv_t, bv, vtw);
  attn_kernel<<<1024, 256, 0, stream>>>(qhw, qlw, khw, klw, vtw, yw);
  gemm_kernel<2><<<dim3(8, 64), 256, 0, stream>>>(
      yw, wp_t, bp, d_out);
}

// Round 14
// 243.696 us; speedup vs baseline: 1.0952x; 1.0667x over previous
//
#include <hip/hip_runtime.h>
#include <stdint.h>
#include <stddef.h>

// Problem constants (B=4, T=2048, C=1024, H=16, hd=64)
#define TT 2048
#define CC 1024
#define BBATCH 4
#define HH 16
#define HD 64
#define MTOT (BBATCH * TT)   // 8192

typedef __bf16 bf16_t;
typedef __bf16 bf16x4 __attribute__((ext_vector_type(4)));
typedef __bf16 bf16x8 __attribute__((ext_vector_type(8)));
typedef float f32x4 __attribute__((ext_vector_type(4)));
typedef float f32x16 __attribute__((ext_vector_type(16)));

typedef const __attribute__((address_space(1))) uint32_t* as1_u32p;
typedef __attribute__((address_space(3))) uint32_t* as3_u32p;

__device__ __forceinline__ f32x4 mfma16(bf16x8 a, bf16x8 b, f32x4 c) {
  return __builtin_amdgcn_mfma_f32_16x16x32_bf16(a, b, c, 0, 0, 0);
}
__device__ __forceinline__ f32x16 mfma32(bf16x8 a, bf16x8 b, f32x16 c) {
  return __builtin_amdgcn_mfma_f32_32x32x16_bf16(a, b, c, 0, 0, 0);
}

// raw v_exp_f32 (2^x), no libm denormal fixup. Args here are <= 0; flush-to-zero
// below 2^-126 is harmless for softmax.
__device__ __forceinline__ float fast_exp2(float x) {
#if __has_builtin(__builtin_amdgcn_exp2f)
  return __builtin_amdgcn_exp2f(x);
#else
  return __expf(x * 0.69314718f);  // fallback: e-base fast exp of x*ln2
#endif
}

// async global->LDS, 16B per lane; lds dest is wave-uniform base + lane*16
__device__ __forceinline__ void gload_lds16(void* lds, const void* g) {
  __builtin_amdgcn_global_load_lds((as1_u32p)g, (as3_u32p)lds, 16, 0, 0);
}

// Fragment read from [rows][32]-bf16 LDS tile (64B rows, swizzle (row>>1)&3).
__device__ __forceinline__ bf16x8 rd32(const char* t, int row, int lane) {
  int sl = (lane >> 4) ^ ((row >> 1) & 3);
  return *(const bf16x8*)(t + row * 64 + sl * 16);
}
// Fragment read from [rows][64]-bf16 LDS tile (128B rows, swizzle row&7), slot = 16B index.
__device__ __forceinline__ bf16x8 rd32r(const char* t, int row, int slot) {
  return *(const bf16x8*)(t + row * 128 + ((slot ^ (row & 7)) * 16));
}

// ---------------- kernel 1: split x (fp32 -> bf16 hi + bf16 lo) ----------------
__global__ void split_x_kernel(const float* __restrict__ x, bf16_t* __restrict__ xh,
                               bf16_t* __restrict__ xl, int n4) {
  int stride = gridDim.x * blockDim.x;
  for (int i = blockIdx.x * blockDim.x + threadIdx.x; i < n4; i += stride) {
    float4 v = ((const float4*)x)[i];
    float vv[4] = {v.x, v.y, v.z, v.w};
    bf16x4 hv, lv;
#pragma unroll
    for (int j = 0; j < 4; ++j) {
      bf16_t h = (bf16_t)vv[j];
      hv[j] = h;
      lv[j] = (bf16_t)(vv[j] - (float)h);
    }
    *(bf16x4*)(xh + (size_t)i * 4) = hv;
    *(bf16x4*)(xl + (size_t)i * 4) = lv;
  }
}

// ------------- kernel 2: transpose weights; split Wq/Wk, plain Wv/Wp -------------
__global__ void transpose_split_kernel(const float* __restrict__ Wq, const float* __restrict__ Wk,
                                       const float* __restrict__ Wv, const float* __restrict__ Wp,
                                       bf16_t* __restrict__ wqkh, bf16_t* __restrict__ wqkl,
                                       bf16_t* __restrict__ wv_t, bf16_t* __restrict__ wp_t) {
  __shared__ float tile[32][33];
  int mat = blockIdx.z;
  const float* W = (mat == 0) ? Wq : (mat == 1) ? Wk : (mat == 2) ? Wv : Wp;
  int tx = threadIdx.x, ty = threadIdx.y;
  int n0 = blockIdx.x * 32, k0 = blockIdx.y * 32;
#pragma unroll
  for (int j = 0; j < 32; j += 8)
    tile[ty + j][tx] = W[(size_t)(k0 + ty + j) * CC + n0 + tx];
  __syncthreads();
#pragma unroll
  for (int j = 0; j < 32; j += 8) {
    float v = tile[tx][ty + j];
    int n = n0 + ty + j, k = k0 + tx;
    if (mat <= 1) {
      bf16_t h = (bf16_t)v;
      size_t o = (size_t)(mat * CC + n) * CC + k;
      wqkh[o] = h;
      wqkl[o] = (bf16_t)(v - (float)h);
    } else {
      bf16_t* dst = (mat == 2) ? wv_t : wp_t;
      dst[(size_t)n * CC + k] = (bf16_t)v;
    }
  }
}

// ------- QK projection GEMM (round-4 best): 256x256, BK=32, 8 waves, dbuf + vmcnt(8) -------
__global__ __launch_bounds__(512, 2) void gemm_qk_kernel(
    const bf16_t* __restrict__ Ah, const bf16_t* __restrict__ Al,
    const bf16_t* __restrict__ Bh, const bf16_t* __restrict__ Bl,
    const float* __restrict__ bq, const float* __restrict__ bk,
    bf16_t* __restrict__ qh, bf16_t* __restrict__ ql,
    bf16_t* __restrict__ kh, bf16_t* __restrict__ kl) {
  __shared__ __align__(16) char s_ah[2][16384];
  __shared__ __align__(16) char s_al[2][16384];
  __shared__ __align__(16) char s_bh[2][16384];
  __shared__ __align__(16) char s_bl[2][16384];

  const int blk = blockIdx.x;
  const int bn = blk & 7;
  const int bm = blk >> 3;
  const int tid = threadIdx.x, w = tid >> 6, lane = tid & 63;
  const int wr = w >> 2, wc = w & 3;          // wave = (wr, wc) of 2x4 -> 128x64 output
  const int qi = lane & 15, hi = lane >> 4;

  const int c0 = w * 2, c1 = w * 2 + 1;
  const int srow0 = c0 * 16 + (lane >> 2);
  const int srow1 = c1 * 16 + (lane >> 2);
  const int ssl0 = (lane & 3) ^ ((srow0 >> 1) & 3);
  const int ssl1 = (lane & 3) ^ ((srow1 >> 1) & 3);
  const size_t a_off0 = (size_t)(bm * 256 + srow0) * CC + ssl0 * 8;
  const size_t a_off1 = (size_t)(bm * 256 + srow1) * CC + ssl1 * 8;
  const size_t b_off0 = (size_t)(bn * 256 + srow0) * CC + ssl0 * 8;
  const size_t b_off1 = (size_t)(bn * 256 + srow1) * CC + ssl1 * 8;

  f32x4 acc[8][4] = {};

#define STAGE_QK(buf, k0)                                        \
  do {                                                           \
    gload_lds16(s_ah[buf] + c0 * 1024, Ah + a_off0 + (k0));      \
    gload_lds16(s_ah[buf] + c1 * 1024, Ah + a_off1 + (k0));      \
    gload_lds16(s_al[buf] + c0 * 1024, Al + a_off0 + (k0));      \
    gload_lds16(s_al[buf] + c1 * 1024, Al + a_off1 + (k0));      \
    gload_lds16(s_bh[buf] + c0 * 1024, Bh + b_off0 + (k0));      \
    gload_lds16(s_bh[buf] + c1 * 1024, Bh + b_off1 + (k0));      \
    gload_lds16(s_bl[buf] + c0 * 1024, Bl + b_off0 + (k0));      \
    gload_lds16(s_bl[buf] + c1 * 1024, Bl + b_off1 + (k0));      \
  } while (0)

  STAGE_QK(0, 0);
  int cur = 0;
  for (int ks = 0; ks < 32; ++ks) {
    if (ks < 31) {
      STAGE_QK(cur ^ 1, (ks + 1) * 32);
      asm volatile("s_waitcnt vmcnt(8)" ::: "memory");  // current tile landed; prefetch in flight
    } else {
      asm volatile("s_waitcnt vmcnt(0)" ::: "memory");
    }
    __builtin_amdgcn_s_barrier();

    bf16x8 bfh[4], bfl[4];
#pragma unroll
    for (int ni = 0; ni < 4; ++ni) {
      int br = wc * 64 + ni * 16 + qi;
      bfh[ni] = rd32(s_bh[cur], br, lane);
      bfl[ni] = rd32(s_bl[cur], br, lane);
    }
    __builtin_amdgcn_s_setprio(1);
#pragma unroll
    for (int mi = 0; mi < 8; ++mi) {
      int ar = wr * 128 + mi * 16 + qi;
      bf16x8 ahf = rd32(s_ah[cur], ar, lane);
      bf16x8 alf = rd32(s_al[cur], ar, lane);
#pragma unroll
      for (int ni = 0; ni < 4; ++ni) {
        acc[mi][ni] = mfma16(ahf, bfh[ni], acc[mi][ni]);
        acc[mi][ni] = mfma16(ahf, bfl[ni], acc[mi][ni]);
        acc[mi][ni] = mfma16(alf, bfh[ni], acc[mi][ni]);
      }
    }
    __builtin_amdgcn_s_setprio(0);
    asm volatile("s_waitcnt lgkmcnt(0)" ::: "memory");
    __builtin_amdgcn_s_barrier();
    cur ^= 1;
  }
#undef STAGE_QK

  // epilogue: bias, Q-scale (1/sqrt(hd) * log2(e) -> exp2-unit logits), split hi/lo
  const int which = bn >> 2;  // 0: Q cols (bn 0..3), 1: K cols (bn 4..7)
  const float* bias = which ? bk : bq;
  bf16_t* oh = which ? kh : qh;
  bf16_t* ol = which ? kl : ql;
#pragma unroll
  for (int mi = 0; mi < 8; ++mi) {
#pragma unroll
    for (int ni = 0; ni < 4; ++ni) {
      const int col = bn * 256 + wc * 64 + ni * 16 + qi;
      const int c1i = col & 1023;
      const int h = c1i >> 6, d = c1i & 63;
#pragma unroll
      for (int r = 0; r < 4; ++r) {
        const int row = bm * 256 + wr * 128 + mi * 16 + hi * 4 + r;
        const int b = row >> 11, t = row & 2047;
        float v = acc[mi][ni][r] + bias[c1i];
        if (!which) v *= 0.18033688f;  // 0.125 * log2(e): softmax done in exp2
        const size_t off = ((size_t)(b * HH + h) * TT + t) * HD + d;
        bf16_t hv = (bf16_t)v;
        oh[off] = hv;
        ol[off] = (bf16_t)(v - (float)hv);
      }
    }
  }
}

// ---------------- GEMM: 128x128 tile, BK=32, 4 waves, 16x16x32 MFMA ----------------
// MODE 1: V projection, plain bf16, N=1024, writes vt [BH][64][T] (transposed)
// MODE 2: output projection, plain bf16 in, fp32 out [M][1024] + bias
template <int MODE>
__global__ __launch_bounds__(256) void gemm_kernel(
    const bf16_t* __restrict__ Ah,
    const bf16_t* __restrict__ Bh,
    const float* __restrict__ bias0,
    void* __restrict__ out0) {
  __shared__ __align__(16) char smem[2 * 8192];
  char* sAh = smem;
  char* sBh = smem + 8192;

  const int bn = blockIdx.x, bm = blockIdx.y;
  const int tid = threadIdx.x, w = tid >> 6, lane = tid & 63;
  const int wr = w >> 1, wc = w & 1;

  f32x4 acc[4][4] = {};

  for (int ks = 0; ks < 32; ++ks) {
    const int k0 = ks * 32;
    __syncthreads();
#pragma unroll
    for (int it = 0; it < 2; ++it) {
      int c = it * 4 + w;                 // 1KB chunk id, uniform per wave
      int row = c * 16 + (lane >> 2);     // tile-local row
      int sl = (lane & 3) ^ ((row >> 1) & 3);  // pre-swizzled source slot
      size_t aoff = (size_t)(bm * 128 + row) * CC + k0 + sl * 8;
      size_t boff = (size_t)(bn * 128 + row) * CC + k0 + sl * 8;
      gload_lds16(sAh + c * 1024, Ah + aoff);
      gload_lds16(sBh + c * 1024, Bh + boff);
    }
    __syncthreads();

    bf16x8 afh[4], bfh[4];
#pragma unroll
    for (int i = 0; i < 4; ++i) {
      int ar = wr * 64 + i * 16 + (lane & 15);
      int br = wc * 64 + i * 16 + (lane & 15);
      afh[i] = rd32(sAh, ar, lane);
      bfh[i] = rd32(sBh, br, lane);
    }
#pragma unroll
    for (int mi = 0; mi < 4; ++mi) {
#pragma unroll
      for (int ni = 0; ni < 4; ++ni) {
        acc[mi][ni] = mfma16(afh[mi], bfh[ni], acc[mi][ni]);
      }
    }
  }

#pragma unroll
  for (int mi = 0; mi < 4; ++mi) {
#pragma unroll
    for (int ni = 0; ni < 4; ++ni) {
      const int col = bn * 128 + wc * 64 + ni * 16 + (lane & 15);
#pragma unroll
      for (int r = 0; r < 4; ++r) {
        const int row = bm * 128 + wr * 64 + mi * 16 + (lane >> 4) * 4 + r;
        float v = acc[mi][ni][r];
        if (MODE == 1) {
          const int h = col >> 6, d = col & 63;
          const int b = row >> 11, t = row & 2047;
          float vv = v + bias0[col];
          ((bf16_t*)out0)[((size_t)(b * HH + h) * HD + d) * TT + t] = (bf16_t)vv;
        } else {
          ((float*)out0)[(size_t)row * CC + col] = v + bias0[col];
        }
      }
    }
  }
}

// ------- flash attention v5.2 (round-8 best + raw v_exp_f32 softmax) -------
// Grid 1024 = 16 qb-batches (heaviest first) x 64 bh. Block handles one 128-row q-block
// (4 waves x 32 q). bh <-> blk mod 64 fixed -> same XCD each qb-batch for K/V L2 reuse.
// Logits arrive pre-scaled by log2(e) (folded into Q projection) -> bare v_exp_f32.
__global__ __launch_bounds__(256, 3) void attn_kernel(
    const bf16_t* __restrict__ qh, const bf16_t* __restrict__ ql,
    const bf16_t* __restrict__ kh, const bf16_t* __restrict__ kl,
    const bf16_t* __restrict__ vt, bf16_t* __restrict__ y) {
  __shared__ __align__(16) char s_kh[2][8192];
  __shared__ __align__(16) char s_kl[2][8192];
  __shared__ __align__(16) char s_vt[2][8192];

  const int blk = blockIdx.x;
  const int qb = 15 - (blk >> 6);                    // LPT: heaviest q-blocks first
  const int bh = (blk & 7) * 8 + ((blk >> 3) & 7);   // XCD-stable per bh
  const int b = bh >> 4, h = bh & 15;
  const int tid = threadIdx.x, w = tid >> 6, lane = tid & 63;
  const int l31 = lane & 31, hi = lane >> 5;

  // staging: wave w stages rows w*16 .. w*16+15 of each 64-row tile (2 gloads/tensor)
  const int strow0 = w * 16 + (lane >> 3);
  const int strow1 = strow0 + 8;
  const int sl0 = (lane & 7) ^ (strow0 & 7);
  const int sl1 = (lane & 7) ^ (strow1 & 7);
  // K rows sigma-permuted: LDS position r holds true kv = swap-bits-2,3(r)
  const int ksrow0 = (strow0 & ~12) | ((strow0 & 4) << 1) | ((strow0 & 8) >> 1);
  const int ksrow1 = (strow1 & ~12) | ((strow1 & 4) << 1) | ((strow1 & 8) >> 1);
  const size_t koff0 = ((size_t)bh * TT + ksrow0) * HD + sl0 * 8;
  const size_t koff1 = ((size_t)bh * TT + ksrow1) * HD + sl1 * 8;
  const size_t voff0 = ((size_t)bh * HD + strow0) * TT + sl0 * 8;
  const size_t voff1 = ((size_t)bh * HD + strow1) * TT + sl1 * 8;
  const int ch0 = (w * 2) * 1024, ch1 = (w * 2 + 1) * 1024;

#define STAGE_ATTN(buf, kt)                                                  \
  do {                                                                       \
    gload_lds16(s_kh[buf] + ch0, kh + koff0 + (size_t)(kt) * 64 * HD);       \
    gload_lds16(s_kh[buf] + ch1, kh + koff1 + (size_t)(kt) * 64 * HD);       \
    gload_lds16(s_kl[buf] + ch0, kl + koff0 + (size_t)(kt) * 64 * HD);       \
    gload_lds16(s_kl[buf] + ch1, kl + koff1 + (size_t)(kt) * 64 * HD);       \
    gload_lds16(s_vt[buf] + ch0, vt + voff0 + (size_t)(kt) * 64);            \
    gload_lds16(s_vt[buf] + ch1, vt + voff1 + (size_t)(kt) * 64);            \
  } while (0)

  const int ktmax = 2 * qb + 1;          // tiles 0..ktmax
  const int qrow0 = qb * 128 + w * 32;   // this wave's first q row
  const int qv = qrow0 + l31;            // this lane's q row

  // Q fragments (hi+lo): B-operand of 32x32x16: col=lane&31 -> q, k = kc*16 + hi*8 + j
  bf16x8 qhf[4], qlf[4];
#pragma unroll
  for (int kc = 0; kc < 4; ++kc) {
    size_t off = ((size_t)bh * TT + qv) * HD + kc * 16 + hi * 8;
    qhf[kc] = *(const bf16x8*)(qh + off);
    qlf[kc] = *(const bf16x8*)(ql + off);
  }

  // O^T accumulators: lane holds O[d][qv], d = dt*32 + (r&3) + 8*(r>>2) + 4*hi
  f32x16 o0 = {}, o1 = {};
  float m = -1e30f, l = 0.f;

  STAGE_ATTN(0, 0);
  int cur = 0;
  for (int kt = 0; kt <= ktmax; ++kt) {
    if (kt < ktmax) {
      STAGE_ATTN(cur ^ 1, kt + 1);
      asm volatile("s_waitcnt vmcnt(6)" ::: "memory");  // current tile landed
    } else {
      asm volatile("s_waitcnt vmcnt(0)" ::: "memory");
    }
    __builtin_amdgcn_s_barrier();

    const char* ckh = s_kh[cur];
    const char* ckl = s_kl[cur];
    const char* cvt = s_vt[cur];
    const bool active = (qrow0 + 31 >= kt * 64);  // wave-uniform
    if (active) {
      // S^T = K*Q^T (3-term). Subtile c covers LDS K rows c*32..c*32+31.
      f32x16 s0 = {}, s1 = {};
#pragma unroll
      for (int kc = 0; kc < 4; ++kc) {
        bf16x8 kfh = rd32r(ckh, l31, kc * 2 + hi);
        bf16x8 kfl = rd32r(ckl, l31, kc * 2 + hi);
        s0 = mfma32(kfh, qhf[kc], s0);
        s0 = mfma32(kfl, qhf[kc], s0);
        s0 = mfma32(kfh, qlf[kc], s0);
      }
#pragma unroll
      for (int kc = 0; kc < 4; ++kc) {
        bf16x8 kfh = rd32r(ckh, 32 + l31, kc * 2 + hi);
        bf16x8 kfl = rd32r(ckl, 32 + l31, kc * 2 + hi);
        s1 = mfma32(kfh, qhf[kc], s1);
        s1 = mfma32(kfl, qhf[kc], s1);
        s1 = mfma32(kfh, qlf[kc], s1);
      }

      // causal mask. True kv of reg r, subtile c: (r&7) + 8*hi + 16*(r>>3) + 32*c
      if (kt * 64 + 63 > qrow0) {
#pragma unroll
        for (int r = 0; r < 16; ++r) {
          const int kvb = kt * 64 + (r & 7) + 8 * hi + 16 * (r >> 3);
          if (kvb > qv) s0[r] = -1e30f;
          if (kvb + 32 > qv) s1[r] = -1e30f;
        }
      }

      // row max: tree reduction (depth 5) + partner lane^32
      float t8[8];
#pragma unroll
      for (int r = 0; r < 8; ++r)
        t8[r] = fmaxf(fmaxf(s0[r], s0[r + 8]), fmaxf(s1[r], s1[r + 8]));
      float t4a = fmaxf(t8[0], t8[4]), t4b = fmaxf(t8[1], t8[5]);
      float t4c = fmaxf(t8[2], t8[6]), t4d = fmaxf(t8[3], t8[7]);
      float tmax = fmaxf(fmaxf(t4a, t4b), fmaxf(t4c, t4d));
      tmax = fmaxf(tmax, __shfl_xor(tmax, 32));

      // exact skip-rescale: if no lane's max grew, sc==1 identically
      const float mnew = fmaxf(m, tmax);
      if (!__all(tmax <= m)) {
        const float sc = fast_exp2(m - mnew);
        l *= sc;
#pragma unroll
        for (int r = 0; r < 16; ++r) { o0[r] *= sc; o1[r] *= sc; }
        m = mnew;
      }

      // P = exp2(S - m) via raw v_exp_f32 (logits pre-scaled by log2 e)
#pragma unroll
      for (int r = 0; r < 16; ++r) {
        s0[r] = fast_exp2(s0[r] - m);
        s1[r] = fast_exp2(s1[r] - m);
      }
      float p8[8];
#pragma unroll
      for (int r = 0; r < 8; ++r)
        p8[r] = (s0[r] + s0[r + 8]) + (s1[r] + s1[r + 8]);
      float ps = ((p8[0] + p8[1]) + (p8[2] + p8[3])) + ((p8[4] + p8[5]) + (p8[6] + p8[7]));
      ps += __shfl_xor(ps, 32);
      l += ps;

      // P fragments: pa[cc] = bf16(S regs 8*(cc&1)+0..7 of subtile cc>>1)
      bf16x8 pa[4];
#pragma unroll
      for (int cc = 0; cc < 4; ++cc) {
#pragma unroll
        for (int j = 0; j < 8; ++j)
          pa[cc][j] = (bf16_t)((cc >> 1) ? s1[8 * (cc & 1) + j] : s0[8 * (cc & 1) + j]);
      }

      // O^T += V^T * P^T: A = V rows (d), k = kv chunk cc
#pragma unroll
      for (int cc = 0; cc < 4; ++cc) {
        bf16x8 vf0 = rd32r(cvt, l31, cc * 2 + hi);
        bf16x8 vf1 = rd32r(cvt, 32 + l31, cc * 2 + hi);
        o0 = mfma32(vf0, pa[cc], o0);
        o1 = mfma32(vf1, pa[cc], o1);
      }
    }

    asm volatile("s_waitcnt lgkmcnt(0)" ::: "memory");
    __builtin_amdgcn_s_barrier();
    cur ^= 1;
  }

  // epilogue: lane holds O[d][qv] for d = dt*32 + g*8 + hi*4 + (0..3)
  const float inv = 1.f / l;
  bf16_t* yb = y + (size_t)(b * TT + qv) * CC + h * HD;
#pragma unroll
  for (int g = 0; g < 4; ++g) {
    bf16x4 ov0, ov1;
#pragma unroll
    for (int r = 0; r < 4; ++r) {
      ov0[r] = (bf16_t)(o0[g * 4 + r] * inv);
      ov1[r] = (bf16_t)(o1[g * 4 + r] * inv);
    }
    *(bf16x4*)(yb + g * 8 + hi * 4) = ov0;
    *(bf16x4*)(yb + 32 + g * 8 + hi * 4) = ov1;
  }
#undef STAGE_ATTN
}

// ---------------- launch ----------------
extern "C" void kernel_launch(void* const* d_in, const int* in_sizes, int n_in,
                              void* d_out, int out_size, void* d_ws, size_t ws_size,
                              hipStream_t stream) {
  (void)in_sizes; (void)n_in; (void)out_size; (void)ws_size;
  const float* x  = (const float*)d_in[0];
  const float* Wq = (const float*)d_in[1];
  const float* bq = (const float*)d_in[2];
  const float* Wk = (const float*)d_in[3];
  const float* bk = (const float*)d_in[4];
  const float* Wv = (const float*)d_in[5];
  const float* bv = (const float*)d_in[6];
  const float* Wp = (const float*)d_in[7];
  const float* bp = (const float*)d_in[8];

  char* ws = (char*)d_ws;
  const size_t MB = 1024 * 1024;
  bf16_t* xh   = (bf16_t*)(ws + 0 * MB);    // [8192][1024]
  bf16_t* xl   = (bf16_t*)(ws + 16 * MB);   // [8192][1024]
  bf16_t* wqkh = (bf16_t*)(ws + 32 * MB);   // [2048][1024] (Wq^T rows 0..1023, Wk^T rows 1024..2047)
  bf16_t* wqkl = (bf16_t*)(ws + 36 * MB);
  bf16_t* wv_t = (bf16_t*)(ws + 40 * MB);   // [1024][1024]
  bf16_t* wp_t = (bf16_t*)(ws + 42 * MB);   // [1024][1024]
  bf16_t* qhw  = (bf16_t*)(ws + 44 * MB);   // [64][2048][64]
  bf16_t* qlw  = (bf16_t*)(ws + 60 * MB);
  bf16_t* khw  = (bf16_t*)(ws + 76 * MB);
  bf16_t* klw  = (bf16_t*)(ws + 92 * MB);
  bf16_t* vtw  = (bf16_t*)(ws + 108 * MB);  // [64][64][2048] (V transposed per head)
  bf16_t* yw   = (bf16_t*)(ws + 124 * MB);  // [8192][1024]

  split_x_kernel<<<2048, 256, 0, stream>>>(x, xh, xl, MTOT * CC / 4);
  transpose_split_kernel<<<dim3(32, 32, 4), dim3(32, 8), 0, stream>>>(
      Wq, Wk, Wv, Wp, wqkh, wqkl, wv_t, wp_t);
  gemm_qk_kernel<<<256, 512, 0, stream>>>(
      xh, xl, wqkh, wqkl, bq, bk, qhw, qlw, khw, klw);
  gemm_kernel<1><<<dim3(8, 64), 256, 0, stream>>>(
      xh, wv_t, bv, vtw);
  attn_kernel<<<1024, 256, 0, stream>>>(qhw, qlw, khw, klw, vtw, yw);
  gemm_kernel<2><<<dim3(8, 64), 256, 0, stream>>>(
      yw, wp_t, bp, d_out);
}